// Round 1
// baseline (484.905 us; speedup 1.0000x reference)
//
#include <hip/hip_runtime.h>
#include <stdint.h>

#define BB 4
#define TT 4096
#define DD 64
#define QBLK 32
#define KBLK 64
#define NIT (TT / KBLK)

typedef short short8 __attribute__((ext_vector_type(8)));
typedef float f32x4 __attribute__((ext_vector_type(4)));

__device__ __forceinline__ uint16_t f2bf(float x) {
  uint32_t u = __float_as_uint(x);
  u += 0x7FFFu + ((u >> 16) & 1u);
  return (uint16_t)(u >> 16);
}
__device__ __forceinline__ float bf2f(uint16_t h) {
  return __uint_as_float(((uint32_t)h) << 16);
}

#define MFMA(a, b, c) __builtin_amdgcn_mfma_f32_16x16x32_bf16((a), (b), (c), 0, 0, 0)

// ---- pre-pass: fp32 -> bf16 hi/lo (Q scaled by 1/64 exactly), V transposed to [B][D][T] ----
__global__ __launch_bounds__(256) void prep_kernel(
    const float* __restrict__ Q, const float* __restrict__ K, const float* __restrict__ V,
    uint16_t* __restrict__ Qh, uint16_t* __restrict__ Ql,
    uint16_t* __restrict__ Kh, uint16_t* __restrict__ Kl,
    uint16_t* __restrict__ Vh, uint16_t* __restrict__ Vl) {
  __shared__ float vt[64][65];
  const int blk = blockIdx.x;        // 256 blocks: (b, 64-row tile)
  const int b = blk >> 6;
  const int r0 = (blk & 63) << 6;
  const int t = threadIdx.x;
  const size_t base = ((size_t)b * TT + r0) * DD;
  for (int i = t; i < 64 * 64; i += 256) {
    float q = Q[base + i] * 0.015625f;   // fold 1/dk scale (exact, pow2)
    uint16_t h = f2bf(q);
    Qh[base + i] = h;
    Ql[base + i] = f2bf(q - bf2f(h));
    float k = K[base + i];
    h = f2bf(k);
    Kh[base + i] = h;
    Kl[base + i] = f2bf(k - bf2f(h));
    int r = i >> 6, c = i & 63;
    vt[r][c] = V[base + i];
  }
  __syncthreads();
  for (int i = t; i < 64 * 64; i += 256) {
    int d = i >> 6, c = i & 63;          // c = local key index
    float v = vt[c][d];
    uint16_t h = f2bf(v);
    size_t o = ((size_t)b * DD + d) * TT + r0 + c;
    Vh[o] = h;
    Vl[o] = f2bf(v - bf2f(h));
  }
}

// ---- flash-attention forward ----
__global__ __launch_bounds__(128) void attn_kernel(
    const float* __restrict__ mask, float* __restrict__ out,
    const uint16_t* __restrict__ Qh, const uint16_t* __restrict__ Ql,
    const uint16_t* __restrict__ Kh, const uint16_t* __restrict__ Kl,
    const uint16_t* __restrict__ Vh, const uint16_t* __restrict__ Vl) {
  // pad inner dim 64 -> 72 (stride 144B = 36 banks -> 4-bank offset/row; kills 16-way conflicts)
  __shared__ uint16_t Kh_s[64][72], Kl_s[64][72];   // [key][d]
  __shared__ uint16_t Vh_s[64][72], Vl_s[64][72];   // [d][key]
  __shared__ uint16_t Ph_s[2][16][72], Pl_s[2][16][72];  // per-wave P, [row][key]

  const int blk = blockIdx.x;
  // XCD swizzle (assumes xcd = blockIdx % 8): batch b -> XCDs {2b, 2b+1};
  // K/V bf16 working set per batch = 2 MiB < 4 MiB per-XCD L2.
  const int xcd = blk & 7;
  const int b = xcd >> 1;
  const int qtile = ((blk >> 3) << 1) | (xcd & 1);  // bijective over 0..127
  const int q0 = qtile * QBLK;
  const int t = threadIdx.x;
  const int w = t >> 6;      // wave 0/1 -> q rows q0+w*16 ..
  const int l = t & 63;
  const int lr = l & 15;
  const int lq = l >> 4;

  // Q A-fragments: row = lr, k(d) = c*32 + lq*8 + [0..7]
  const uint16_t* qhp = Qh + ((size_t)b * TT + q0 + w * 16 + lr) * DD + lq * 8;
  const uint16_t* qlp = Ql + ((size_t)b * TT + q0 + w * 16 + lr) * DD + lq * 8;
  short8 qh[2], ql[2];
  qh[0] = *(const short8*)(qhp);
  qh[1] = *(const short8*)(qhp + 32);
  ql[0] = *(const short8*)(qlp);
  ql[1] = *(const short8*)(qlp + 32);

  f32x4 o[4];
  float mrow[4], lrow[4];
#pragma unroll
  for (int dt = 0; dt < 4; ++dt) o[dt] = (f32x4){0.f, 0.f, 0.f, 0.f};
#pragma unroll
  for (int j = 0; j < 4; ++j) { mrow[j] = -1e30f; lrow[j] = 0.f; }

  // mask row pointers (D-layout rows: q0 + w*16 + lq*4 + j)
  const float* mp[4];
#pragma unroll
  for (int j = 0; j < 4; ++j)
    mp[j] = mask + ((size_t)b * TT + q0 + w * 16 + lq * 4 + j) * TT + lr;

  // prefetch mask tile 0 (nontemporal: pure stream, keep L2 for K/V)
  float mk[16];
#pragma unroll
  for (int tt = 0; tt < 4; ++tt)
#pragma unroll
    for (int j = 0; j < 4; ++j)
      mk[tt * 4 + j] = __builtin_nontemporal_load(mp[j] + tt * 16);

  const size_t kvb = (size_t)b * TT * DD;
  const size_t vtb = (size_t)b * DD * TT;

  for (int it = 0; it < NIT; ++it) {
    const int s0 = it * KBLK;
    __syncthreads();
    // ---- stage K/V bf16 tile into LDS (128 threads x 4 chunks x 4 arrays) ----
#pragma unroll
    for (int i = 0; i < 4; ++i) {
      const int idx = i * 128 + t;
      const int row = idx >> 3, c = idx & 7;
      const size_t ko = kvb + (size_t)(s0 + row) * DD + c * 8;
      *(short8*)&Kh_s[row][c * 8] = *(const short8*)(Kh + ko);
      *(short8*)&Kl_s[row][c * 8] = *(const short8*)(Kl + ko);
      const size_t vo = vtb + (size_t)row * TT + s0 + c * 8;  // row = d
      *(short8*)&Vh_s[row][c * 8] = *(const short8*)(Vh + vo);
      *(short8*)&Vl_s[row][c * 8] = *(const short8*)(Vl + vo);
    }
    __syncthreads();

    // ---- prefetch NEXT mask tile (hide HBM latency under this tile's compute) ----
    float mk2[16];
    if (it + 1 < NIT) {
#pragma unroll
      for (int tt = 0; tt < 4; ++tt)
#pragma unroll
        for (int j = 0; j < 4; ++j)
          mk2[tt * 4 + j] = __builtin_nontemporal_load(mp[j] + (s0 + KBLK) + tt * 16);
    } else {
#pragma unroll
      for (int i = 0; i < 16; ++i) mk2[i] = 0.f;
    }

    // ---- S = (Q/64)·K^T via 3-term bf16 split ----
    f32x4 s[4];
#pragma unroll
    for (int tt = 0; tt < 4; ++tt) {
      f32x4 acc = (f32x4){0.f, 0.f, 0.f, 0.f};
#pragma unroll
      for (int c = 0; c < 2; ++c) {
        const short8 bh = *(const short8*)&Kh_s[tt * 16 + lr][c * 32 + lq * 8];
        const short8 bl = *(const short8*)&Kl_s[tt * 16 + lr][c * 32 + lq * 8];
        acc = MFMA(qh[c], bh, acc);
        acc = MFMA(ql[c], bh, acc);
        acc = MFMA(qh[c], bl, acc);
      }
      s[tt] = acc;
    }
#pragma unroll
    for (int tt = 0; tt < 4; ++tt)
#pragma unroll
      for (int j = 0; j < 4; ++j) s[tt][j] += mk[tt * 4 + j];

    // ---- online softmax (rows live on 16-lane groups, reg j = row lq*4+j) ----
    float cm[4];
#pragma unroll
    for (int j = 0; j < 4; ++j)
      cm[j] = fmaxf(fmaxf(s[0][j], s[1][j]), fmaxf(s[2][j], s[3][j]));
#pragma unroll
    for (int d = 1; d < 16; d <<= 1)
#pragma unroll
      for (int j = 0; j < 4; ++j) cm[j] = fmaxf(cm[j], __shfl_xor(cm[j], d, 16));
    float scl[4];
#pragma unroll
    for (int j = 0; j < 4; ++j) {
      const float mn = fmaxf(mrow[j], cm[j]);
      scl[j] = __expf(mrow[j] - mn);
      mrow[j] = mn;
    }
#pragma unroll
    for (int tt = 0; tt < 4; ++tt)
#pragma unroll
      for (int j = 0; j < 4; ++j) s[tt][j] = __expf(s[tt][j] - mrow[j]);
    float rs[4];
#pragma unroll
    for (int j = 0; j < 4; ++j) rs[j] = (s[0][j] + s[1][j]) + (s[2][j] + s[3][j]);
#pragma unroll
    for (int d = 1; d < 16; d <<= 1)
#pragma unroll
      for (int j = 0; j < 4; ++j) rs[j] += __shfl_xor(rs[j], d, 16);
#pragma unroll
    for (int j = 0; j < 4; ++j) lrow[j] = lrow[j] * scl[j] + rs[j];
#pragma unroll
    for (int dt = 0; dt < 4; ++dt)
#pragma unroll
      for (int j = 0; j < 4; ++j) o[dt][j] *= scl[j];

    // ---- P (D-layout) -> bf16 hi/lo in LDS (A-layout re-read below) ----
#pragma unroll
    for (int tt = 0; tt < 4; ++tt)
#pragma unroll
      for (int j = 0; j < 4; ++j) {
        const float p = s[tt][j];
        const uint16_t h = f2bf(p);
        Ph_s[w][lq * 4 + j][tt * 16 + lr] = h;
        Pl_s[w][lq * 4 + j][tt * 16 + lr] = f2bf(p - bf2f(h));
      }

    // ---- O += P·V via 3-term bf16 split ----
#pragma unroll
    for (int c = 0; c < 2; ++c) {
      const short8 ph = *(const short8*)&Ph_s[w][lr][c * 32 + lq * 8];
      const short8 pl = *(const short8*)&Pl_s[w][lr][c * 32 + lq * 8];
#pragma unroll
      for (int dt = 0; dt < 4; ++dt) {
        const short8 vh = *(const short8*)&Vh_s[dt * 16 + lr][c * 32 + lq * 8];
        const short8 vl = *(const short8*)&Vl_s[dt * 16 + lr][c * 32 + lq * 8];
        o[dt] = MFMA(ph, vh, o[dt]);
        o[dt] = MFMA(pl, vh, o[dt]);
        o[dt] = MFMA(ph, vl, o[dt]);
      }
    }

#pragma unroll
    for (int i = 0; i < 16; ++i) mk[i] = mk2[i];
  }

  // ---- epilogue: O / l ----
#pragma unroll
  for (int j = 0; j < 4; ++j) {
    const float inv = 1.0f / lrow[j];
    const size_t ob = ((size_t)b * TT + q0 + w * 16 + lq * 4 + j) * DD + lr;
#pragma unroll
    for (int dt = 0; dt < 4; ++dt) out[ob + dt * 16] = o[dt][j] * inv;
  }
}

extern "C" void kernel_launch(void* const* d_in, const int* in_sizes, int n_in,
                              void* d_out, int out_size, void* d_ws, size_t ws_size,
                              hipStream_t stream) {
  const float* Q = (const float*)d_in[0];
  const float* K = (const float*)d_in[1];
  const float* V = (const float*)d_in[2];
  const float* mask = (const float*)d_in[3];
  float* out = (float*)d_out;

  const size_t NE = (size_t)BB * TT * DD;  // 1M elements per array
  uint16_t* ws = (uint16_t*)d_ws;          // needs 12 MiB
  uint16_t* Qh = ws;
  uint16_t* Ql = ws + NE;
  uint16_t* Kh = ws + 2 * NE;
  uint16_t* Kl = ws + 3 * NE;
  uint16_t* Vh = ws + 4 * NE;
  uint16_t* Vl = ws + 5 * NE;

  prep_kernel<<<dim3(256), dim3(256), 0, stream>>>(Q, K, V, Qh, Ql, Kh, Kl, Vh, Vl);
  attn_kernel<<<dim3(512), dim3(128), 0, stream>>>(mask, out, Qh, Ql, Kh, Kl, Vh, Vl);
}

// Round 6
// 422.483 us; speedup vs baseline: 1.1477x; 1.1477x over previous
//
#include <hip/hip_runtime.h>
#include <stdint.h>

#define BB 4
#define TT 4096
#define DD 64
#define KBLK 64

typedef short short8 __attribute__((ext_vector_type(8)));
typedef float f32x4 __attribute__((ext_vector_type(4)));

__device__ __forceinline__ uint16_t f2bf(float x) {
  uint32_t u = __float_as_uint(x);
  u += 0x7FFFu + ((u >> 16) & 1u);
  return (uint16_t)(u >> 16);
}
__device__ __forceinline__ float bf2f(uint16_t h) {
  return __uint_as_float(((uint32_t)h) << 16);
}

#define MFMA(a, b, c) __builtin_amdgcn_mfma_f32_16x16x32_bf16((a), (b), (c), 0, 0, 0)

// ---- pre-pass: fp32 -> bf16 hi/lo (Q scaled by 1/64 exactly), V transposed to [B][D][T] ----
__global__ __launch_bounds__(256) void prep_kernel(
    const float* __restrict__ Q, const float* __restrict__ K, const float* __restrict__ V,
    uint16_t* __restrict__ Qh, uint16_t* __restrict__ Ql,
    uint16_t* __restrict__ Kh, uint16_t* __restrict__ Kl,
    uint16_t* __restrict__ Vh, uint16_t* __restrict__ Vl) {
  __shared__ float vt[64][65];
  const int blk = blockIdx.x;  // 256 blocks: (b, 64-row tile)
  const int b = blk >> 6;
  const int r0 = (blk & 63) << 6;
  const int t = threadIdx.x;
  const size_t base = ((size_t)b * TT + r0) * DD;
  for (int i = t; i < 64 * 64; i += 256) {
    float q = Q[base + i] * 0.015625f;  // fold 1/dk scale (exact, pow2)
    uint16_t h = f2bf(q);
    Qh[base + i] = h;
    Ql[base + i] = f2bf(q - bf2f(h));
    float k = K[base + i];
    h = f2bf(k);
    Kh[base + i] = h;
    Kl[base + i] = f2bf(k - bf2f(h));
    int r = i >> 6, c = i & 63;
    vt[r][c] = V[base + i];
  }
  __syncthreads();
  for (int i = t; i < 64 * 64; i += 256) {
    int d = i >> 6, c = i & 63;  // c = local key index
    float v = vt[c][d];
    uint16_t h = f2bf(v);
    size_t o = ((size_t)b * DD + d) * TT + r0 + c;
    Vh[o] = h;
    Vl[o] = f2bf(v - bf2f(h));
  }
}

// ---- flash-attention forward, split-K partials ----
// Block: NW waves, each wave owns 16 q-rows (RPB = NW*16 rows/block), all waves share
// one key segment of TT/NSEG keys staged tile-by-tile in LDS.
// Grid: (16384/RPB) * NSEG blocks. Partials (m,l,O) -> workspace unless NSEG==1.
template <int NSEG, int NW>
__global__ __launch_bounds__(NW * 64, 4) void attn_kernel(
    const float* __restrict__ mask, float* __restrict__ out,
    float* __restrict__ Op, float* __restrict__ Mp, float* __restrict__ Lp,
    const uint16_t* __restrict__ Qh, const uint16_t* __restrict__ Ql,
    const uint16_t* __restrict__ Kh, const uint16_t* __restrict__ Kl,
    const uint16_t* __restrict__ Vh, const uint16_t* __restrict__ Vl) {
  constexpr int RPB = NW * 16;
  constexpr int PBH = (TT / RPB) / 2;  // per-batch row-blocks / 2 XCDs
  constexpr int SEGLEN = TT / NSEG;
  constexpr int NIT = SEGLEN / KBLK;

  // pad inner dim 64 -> 72 (stride 144B: 2-way max bank aliasing on b128 reads)
  __shared__ uint16_t Kh_s[64][72], Kl_s[64][72];  // [key][d]
  __shared__ uint16_t Vh_s[64][72], Vl_s[64][72];  // [d][key]
  __shared__ uint16_t Ph_s[NW][16][72], Pl_s[NW][16][72];

  const int bid = blockIdx.x;
  // XCD swizzle (xcd = blockIdx % 8): batch b -> XCDs {2b,2b+1}; per-XCD K/V set 2 MiB.
  const int xcd = bid & 7;
  const int b = xcd >> 1;
  const int u = bid >> 3;
  const int rbl = (u % PBH) * 2 + (xcd & 1);  // row-block within batch
  const int seg = u / PBH;
  const int q0 = rbl * RPB;
  const int t = threadIdx.x;
  const int w = t >> 6;
  const int l = t & 63;
  const int lr = l & 15;
  const int lq = l >> 4;
  const int qrow = q0 + w * 16;  // wave's first q-row within batch
  const int sb = seg * SEGLEN;

  // Q A-fragments: row = lr, k(d) = c*32 + lq*8 + [0..7]
  const uint16_t* qhp = Qh + ((size_t)b * TT + qrow + lr) * DD + lq * 8;
  const uint16_t* qlp = Ql + ((size_t)b * TT + qrow + lr) * DD + lq * 8;
  short8 qh[2], ql[2];
  qh[0] = *(const short8*)(qhp);
  qh[1] = *(const short8*)(qhp + 32);
  ql[0] = *(const short8*)(qlp);
  ql[1] = *(const short8*)(qlp + 32);

  f32x4 o[4];
  float mrow[4], lrow[4];
#pragma unroll
  for (int dt = 0; dt < 4; ++dt) o[dt] = (f32x4){0.f, 0.f, 0.f, 0.f};
#pragma unroll
  for (int j = 0; j < 4; ++j) { mrow[j] = -1e30f; lrow[j] = 0.f; }

  // mask row pointers (D-layout rows: qrow + lq*4 + j), segment base folded in
  const float* mp[4];
#pragma unroll
  for (int j = 0; j < 4; ++j)
    mp[j] = mask + ((size_t)b * TT + qrow + lq * 4 + j) * TT + sb + lr;

  // prefetch mask tile 0 (nontemporal: pure stream)
  float mk[16];
#pragma unroll
  for (int tt = 0; tt < 4; ++tt)
#pragma unroll
    for (int j = 0; j < 4; ++j)
      mk[tt * 4 + j] = __builtin_nontemporal_load(mp[j] + tt * 16);

  const size_t kvb = (size_t)b * TT * DD;
  const size_t vtb = (size_t)b * DD * TT;

  for (int it = 0; it < NIT; ++it) {
    const int s0 = sb + it * KBLK;
    __syncthreads();
    // ---- stage K/V bf16 tile into LDS (all NW waves cooperate) ----
    for (int i = t; i < 512; i += NW * 64) {
      const int row = i >> 3, c = i & 7;
      const size_t ko = kvb + (size_t)(s0 + row) * DD + c * 8;
      *(short8*)&Kh_s[row][c * 8] = *(const short8*)(Kh + ko);
      *(short8*)&Kl_s[row][c * 8] = *(const short8*)(Kl + ko);
      const size_t vo = vtb + (size_t)row * TT + s0 + c * 8;  // row = d
      *(short8*)&Vh_s[row][c * 8] = *(const short8*)(Vh + vo);
      *(short8*)&Vl_s[row][c * 8] = *(const short8*)(Vl + vo);
    }
    __syncthreads();

    // ---- prefetch NEXT mask tile (consumed next iteration) ----
    float mk2[16];
    if (it + 1 < NIT) {
#pragma unroll
      for (int tt = 0; tt < 4; ++tt)
#pragma unroll
        for (int j = 0; j < 4; ++j)
          mk2[tt * 4 + j] = __builtin_nontemporal_load(mp[j] + (it + 1) * KBLK + tt * 16);
    } else {
#pragma unroll
      for (int i = 0; i < 16; ++i) mk2[i] = 0.f;
    }

    // ---- S = (Q/64)·K^T via 3-term bf16 split ----
    f32x4 s[4];
#pragma unroll
    for (int tt = 0; tt < 4; ++tt) {
      f32x4 acc = (f32x4){0.f, 0.f, 0.f, 0.f};
#pragma unroll
      for (int c = 0; c < 2; ++c) {
        const short8 bh = *(const short8*)&Kh_s[tt * 16 + lr][c * 32 + lq * 8];
        const short8 bl = *(const short8*)&Kl_s[tt * 16 + lr][c * 32 + lq * 8];
        acc = MFMA(qh[c], bh, acc);
        acc = MFMA(ql[c], bh, acc);
        acc = MFMA(qh[c], bl, acc);
      }
      s[tt] = acc;
    }
#pragma unroll
    for (int tt = 0; tt < 4; ++tt)
#pragma unroll
      for (int j = 0; j < 4; ++j) s[tt][j] += mk[tt * 4 + j];

    // ---- online softmax (rows live on 16-lane groups, reg j = row lq*4+j) ----
    float cm[4];
#pragma unroll
    for (int j = 0; j < 4; ++j)
      cm[j] = fmaxf(fmaxf(s[0][j], s[1][j]), fmaxf(s[2][j], s[3][j]));
#pragma unroll
    for (int d = 1; d < 16; d <<= 1)
#pragma unroll
      for (int j = 0; j < 4; ++j) cm[j] = fmaxf(cm[j], __shfl_xor(cm[j], d, 16));
    float scl[4];
#pragma unroll
    for (int j = 0; j < 4; ++j) {
      const float mn = fmaxf(mrow[j], cm[j]);
      scl[j] = __expf(mrow[j] - mn);
      mrow[j] = mn;
    }
#pragma unroll
    for (int tt = 0; tt < 4; ++tt)
#pragma unroll
      for (int j = 0; j < 4; ++j) s[tt][j] = __expf(s[tt][j] - mrow[j]);
    float rs[4];
#pragma unroll
    for (int j = 0; j < 4; ++j) rs[j] = (s[0][j] + s[1][j]) + (s[2][j] + s[3][j]);
#pragma unroll
    for (int d = 1; d < 16; d <<= 1)
#pragma unroll
      for (int j = 0; j < 4; ++j) rs[j] += __shfl_xor(rs[j], d, 16);
#pragma unroll
    for (int j = 0; j < 4; ++j) lrow[j] = lrow[j] * scl[j] + rs[j];
#pragma unroll
    for (int dt = 0; dt < 4; ++dt)
#pragma unroll
      for (int j = 0; j < 4; ++j) o[dt][j] *= scl[j];

    // ---- P (D-layout) -> bf16 hi/lo in per-wave LDS (no barrier: same wave) ----
#pragma unroll
    for (int tt = 0; tt < 4; ++tt)
#pragma unroll
      for (int j = 0; j < 4; ++j) {
        const float p = s[tt][j];
        const uint16_t h = f2bf(p);
        Ph_s[w][lq * 4 + j][tt * 16 + lr] = h;
        Pl_s[w][lq * 4 + j][tt * 16 + lr] = f2bf(p - bf2f(h));
      }

    // ---- O += P·V via 3-term bf16 split ----
#pragma unroll
    for (int c = 0; c < 2; ++c) {
      const short8 ph = *(const short8*)&Ph_s[w][lr][c * 32 + lq * 8];
      const short8 pl = *(const short8*)&Pl_s[w][lr][c * 32 + lq * 8];
#pragma unroll
      for (int dt = 0; dt < 4; ++dt) {
        const short8 vh = *(const short8*)&Vh_s[dt * 16 + lr][c * 32 + lq * 8];
        const short8 vl = *(const short8*)&Vl_s[dt * 16 + lr][c * 32 + lq * 8];
        o[dt] = MFMA(ph, vh, o[dt]);
        o[dt] = MFMA(pl, vh, o[dt]);
        o[dt] = MFMA(ph, vl, o[dt]);
      }
    }

#pragma unroll
    for (int i = 0; i < 16; ++i) mk[i] = mk2[i];
  }

  // ---- epilogue ----
  if constexpr (NSEG == 1) {
#pragma unroll
    for (int j = 0; j < 4; ++j) {
      const float inv = 1.0f / lrow[j];
      const size_t ob = ((size_t)b * TT + qrow + lq * 4 + j) * DD + lr;
#pragma unroll
      for (int dt = 0; dt < 4; ++dt) out[ob + dt * 16] = o[dt][j] * inv;
    }
  } else {
    const int grow = b * TT + qrow + lq * 4;  // + j = global row id
#pragma unroll
    for (int j = 0; j < 4; ++j) {
      const size_t r = (size_t)seg * (BB * TT) + grow + j;
#pragma unroll
      for (int dt = 0; dt < 4; ++dt) Op[r * 64 + dt * 16 + lr] = o[dt][j];
      if (lr == 0) { Mp[r] = mrow[j]; Lp[r] = lrow[j]; }
    }
  }
}

// ---- merge NSEG partial results per row ----
__global__ __launch_bounds__(256) void combine_kernel(
    const float* __restrict__ Op, const float* __restrict__ Mp,
    const float* __restrict__ Lp, float* __restrict__ out, int nseg) {
  const int gid = blockIdx.x * 256 + threadIdx.x;
  const int r = gid >> 6, d = gid & 63;
  constexpr int ROWS = BB * TT;
  float m = -3.0e38f;
  for (int s = 0; s < nseg; ++s) m = fmaxf(m, Mp[s * ROWS + r]);
  float num = 0.f, den = 0.f;
  for (int s = 0; s < nseg; ++s) {
    const float e = __expf(Mp[s * ROWS + r] - m);
    den += Lp[s * ROWS + r] * e;
    num += Op[((size_t)s * ROWS + r) * 64 + d] * e;
  }
  out[(size_t)r * 64 + d] = num / den;
}

extern "C" void kernel_launch(void* const* d_in, const int* in_sizes, int n_in,
                              void* d_out, int out_size, void* d_ws, size_t ws_size,
                              hipStream_t stream) {
  const float* Q = (const float*)d_in[0];
  const float* K = (const float*)d_in[1];
  const float* V = (const float*)d_in[2];
  const float* mask = (const float*)d_in[3];
  float* out = (float*)d_out;

  const size_t NE = (size_t)BB * TT * DD;  // 1M elements per array
  const size_t ROWS = (size_t)BB * TT;     // 16384
  uint16_t* ws = (uint16_t*)d_ws;          // bf16 arrays: 12 MiB
  uint16_t* Qh = ws;
  uint16_t* Ql = ws + NE;
  uint16_t* Kh = ws + 2 * NE;
  uint16_t* Kl = ws + 3 * NE;
  uint16_t* Vh = ws + 4 * NE;
  uint16_t* Vl = ws + 5 * NE;

  const size_t bf_bytes = 6 * NE * 2;
  const size_t per_seg = ROWS * 64 * 4 + ROWS * 2 * 4;  // O + (m,l)
  int nseg = (ws_size >= bf_bytes + 4 * per_seg) ? 4
           : (ws_size >= bf_bytes + 2 * per_seg) ? 2 : 1;

  char* pbase = (char*)d_ws + bf_bytes;
  float* Op = (float*)pbase;
  float* Mp = (float*)(pbase + (size_t)nseg * ROWS * 64 * 4);
  float* Lp = Mp + (size_t)nseg * ROWS;

  prep_kernel<<<dim3(256), dim3(256), 0, stream>>>(Q, K, V, Qh, Ql, Kh, Kl, Vh, Vl);

  if (nseg == 4) {
    attn_kernel<4, 8><<<dim3(512), dim3(512), 0, stream>>>(
        mask, out, Op, Mp, Lp, Qh, Ql, Kh, Kl, Vh, Vl);
  } else if (nseg == 2) {
    attn_kernel<2, 8><<<dim3(256), dim3(512), 0, stream>>>(
        mask, out, Op, Mp, Lp, Qh, Ql, Kh, Kl, Vh, Vl);
  } else {
    attn_kernel<1, 4><<<dim3(256), dim3(256), 0, stream>>>(
        mask, out, Op, Mp, Lp, Qh, Ql, Kh, Kl, Vh, Vl);
  }
  if (nseg > 1) {
    combine_kernel<<<dim3((ROWS * 64) / 256), dim3(256), 0, stream>>>(Op, Mp, Lp, out, nseg);
  }
}

// Round 8
// 400.045 us; speedup vs baseline: 1.2121x; 1.0561x over previous
//
#include <hip/hip_runtime.h>
#include <stdint.h>

#define BB 4
#define TT 4096
#define DD 64
#define KBLK 64

typedef short short8 __attribute__((ext_vector_type(8)));
typedef float f32x4 __attribute__((ext_vector_type(4)));

__device__ __forceinline__ uint16_t f2bf(float x) {
  uint32_t u = __float_as_uint(x);
  u += 0x7FFFu + ((u >> 16) & 1u);
  return (uint16_t)(u >> 16);
}
__device__ __forceinline__ float bf2f(uint16_t h) {
  return __uint_as_float(((uint32_t)h) << 16);
}
__device__ __forceinline__ uint32_t pkbf(float a, float b) {
  return (uint32_t)f2bf(a) | ((uint32_t)f2bf(b) << 16);
}

#define MFMA(a, b, c) __builtin_amdgcn_mfma_f32_16x16x32_bf16((a), (b), (c), 0, 0, 0)

// ---- pre-pass: fp32 -> bf16 hi/lo (Q scaled by 1/64 exactly), V transposed to [B][D][T] ----
__global__ __launch_bounds__(256) void prep_kernel(
    const float* __restrict__ Q, const float* __restrict__ K, const float* __restrict__ V,
    uint16_t* __restrict__ Qh, uint16_t* __restrict__ Ql,
    uint16_t* __restrict__ Kh, uint16_t* __restrict__ Kl,
    uint16_t* __restrict__ Vh, uint16_t* __restrict__ Vl) {
  __shared__ float vt[64][65];
  const int blk = blockIdx.x;  // 256 blocks: (b, 64-row tile)
  const int b = blk >> 6;
  const int r0 = (blk & 63) << 6;
  const int t = threadIdx.x;
  const size_t base = ((size_t)b * TT + r0) * DD;
  for (int i = t; i < 64 * 64; i += 256) {
    float q = Q[base + i] * 0.015625f;  // fold 1/dk scale (exact, pow2)
    uint16_t h = f2bf(q);
    Qh[base + i] = h;
    Ql[base + i] = f2bf(q - bf2f(h));
    float k = K[base + i];
    h = f2bf(k);
    Kh[base + i] = h;
    Kl[base + i] = f2bf(k - bf2f(h));
    int r = i >> 6, c = i & 63;
    vt[r][c] = V[base + i];
  }
  __syncthreads();
  for (int i = t; i < 64 * 64; i += 256) {
    int d = i >> 6, c = i & 63;  // c = local key index
    float v = vt[c][d];
    uint16_t h = f2bf(v);
    size_t o = ((size_t)b * DD + d) * TT + r0 + c;
    Vh[o] = h;
    Vl[o] = f2bf(v - bf2f(h));
  }
}

// ---- flash-attention forward, split-K partials, S^T (swapped QK^T) layout ----
// Swapped MFMA: S^T = K·Q  ->  D: key = lq*4+j, qrow = lr.  Mask elements per lane are
// key-contiguous -> one float4 nontemporal load per 16-key sub-tile. m/l are per-lane
// scalars (q-row = lr). PV unchanged (P routed via per-wave LDS; O: q=lq*4+j, d=dt*16+lr).
template <int NSEG, int NW>
__global__ __launch_bounds__(NW * 64, 4) void attn_kernel(
    const float* __restrict__ mask, float* __restrict__ out,
    float* __restrict__ Op, float* __restrict__ Mp, float* __restrict__ Lp,
    const uint16_t* __restrict__ Qh, const uint16_t* __restrict__ Ql,
    const uint16_t* __restrict__ Kh, const uint16_t* __restrict__ Kl,
    const uint16_t* __restrict__ Vh, const uint16_t* __restrict__ Vl) {
  constexpr int RPB = NW * 16;
  constexpr int PBH = (TT / RPB) / 2;  // per-batch row-blocks / 2 XCDs
  constexpr int SEGLEN = TT / NSEG;
  constexpr int NIT = SEGLEN / KBLK;

  // pad inner dim 64 -> 72 (stride 144B: 2-way max bank aliasing on b128 reads)
  __shared__ uint16_t Kh_s[64][72], Kl_s[64][72];  // [key][d]
  __shared__ uint16_t Vh_s[64][72], Vl_s[64][72];  // [d][key]
  __shared__ uint16_t Ph_s[NW][16][72], Pl_s[NW][16][72];  // [qrow][key]

  const int bid = blockIdx.x;
  // XCD swizzle (xcd = blockIdx % 8): batch b -> XCDs {2b,2b+1}; per-XCD K/V set 2 MiB.
  const int xcd = bid & 7;
  const int b = xcd >> 1;
  const int u = bid >> 3;
  const int rbl = (u % PBH) * 2 + (xcd & 1);  // row-block within batch
  const int seg = u / PBH;
  const int q0 = rbl * RPB;
  const int t = threadIdx.x;
  const int w = t >> 6;
  const int l = t & 63;
  const int lr = l & 15;
  const int lq = l >> 4;
  const int qrow = q0 + w * 16;  // wave's first q-row within batch
  const int sb = seg * SEGLEN;

  // Q fragment (B-operand): col(q-row) = lr, k(d) = c*32 + lq*8 + [0..7]
  const uint16_t* qhp = Qh + ((size_t)b * TT + qrow + lr) * DD + lq * 8;
  const uint16_t* qlp = Ql + ((size_t)b * TT + qrow + lr) * DD + lq * 8;
  short8 qh[2], ql[2];
  qh[0] = *(const short8*)(qhp);
  qh[1] = *(const short8*)(qhp + 32);
  ql[0] = *(const short8*)(qlp);
  ql[1] = *(const short8*)(qlp + 32);

  f32x4 o[4];
  float mrow = -1e30f, lrow = 0.f;  // per-lane: q-row = lr
#pragma unroll
  for (int dt = 0; dt < 4; ++dt) o[dt] = (f32x4){0.f, 0.f, 0.f, 0.f};

  // one mask row per lane (q-row = lr); lane's 4 keys are contiguous: 16*tt + 4*lq + j
  const float* mprow = mask + ((size_t)b * TT + qrow + lr) * TT + sb + lq * 4;

  // prefetch mask tile 0 (nontemporal: pure stream)
  f32x4 mk[4];
#pragma unroll
  for (int tt = 0; tt < 4; ++tt)
    mk[tt] = __builtin_nontemporal_load((const f32x4*)(mprow + tt * 16));

  const size_t kvb = (size_t)b * TT * DD;
  const size_t vtb = (size_t)b * DD * TT;

  for (int it = 0; it < NIT; ++it) {
    const int s0 = sb + it * KBLK;
    __syncthreads();
    // ---- stage K/V bf16 tile into LDS (all NW waves cooperate) ----
    for (int i = t; i < 512; i += NW * 64) {
      const int row = i >> 3, c = i & 7;
      const size_t ko = kvb + (size_t)(s0 + row) * DD + c * 8;
      *(short8*)&Kh_s[row][c * 8] = *(const short8*)(Kh + ko);
      *(short8*)&Kl_s[row][c * 8] = *(const short8*)(Kl + ko);
      const size_t vo = vtb + (size_t)row * TT + s0 + c * 8;  // row = d
      *(short8*)&Vh_s[row][c * 8] = *(const short8*)(Vh + vo);
      *(short8*)&Vl_s[row][c * 8] = *(const short8*)(Vl + vo);
    }
    __syncthreads();

    // ---- prefetch NEXT mask tile (consumed next iteration) ----
    f32x4 mk2[4];
    if (it + 1 < NIT) {
#pragma unroll
      for (int tt = 0; tt < 4; ++tt)
        mk2[tt] = __builtin_nontemporal_load((const f32x4*)(mprow + (it + 1) * KBLK + tt * 16));
    } else {
#pragma unroll
      for (int tt = 0; tt < 4; ++tt) mk2[tt] = (f32x4){0.f, 0.f, 0.f, 0.f};
    }

    // ---- S^T = K·(Q/64) via 3-term bf16 split; s[tt][j]: key=16tt+4lq+j, q=lr ----
    f32x4 s[4];
#pragma unroll
    for (int tt = 0; tt < 4; ++tt) {
      f32x4 acc = (f32x4){0.f, 0.f, 0.f, 0.f};
#pragma unroll
      for (int c = 0; c < 2; ++c) {
        const short8 bh = *(const short8*)&Kh_s[tt * 16 + lr][c * 32 + lq * 8];
        const short8 bl = *(const short8*)&Kl_s[tt * 16 + lr][c * 32 + lq * 8];
        acc = MFMA(bh, qh[c], acc);
        acc = MFMA(bl, qh[c], acc);
        acc = MFMA(bh, ql[c], acc);
      }
      s[tt] = acc;
    }
#pragma unroll
    for (int tt = 0; tt < 4; ++tt) s[tt] += mk[tt];

    // ---- online softmax: row = lane's lr; reduce across the 4 lq groups (2 shfl) ----
    float cm = fmaxf(fmaxf(fmaxf(s[0][0], s[0][1]), fmaxf(s[0][2], s[0][3])),
                     fmaxf(fmaxf(s[1][0], s[1][1]), fmaxf(s[1][2], s[1][3])));
    cm = fmaxf(cm, fmaxf(fmaxf(fmaxf(s[2][0], s[2][1]), fmaxf(s[2][2], s[2][3])),
                         fmaxf(fmaxf(s[3][0], s[3][1]), fmaxf(s[3][2], s[3][3]))));
    cm = fmaxf(cm, __shfl_xor(cm, 16));
    cm = fmaxf(cm, __shfl_xor(cm, 32));
    // defer-max (T13): skip O-rescale while max growth stays within e^8 headroom
    if (!__all(cm <= mrow + 8.0f)) {
      const float mn = fmaxf(mrow, cm);
      const float scl = __expf(mrow - mn);
      mrow = mn;
      lrow *= scl;
      float sj[4];
#pragma unroll
      for (int j = 0; j < 4; ++j) sj[j] = __shfl(scl, lq * 4 + j);  // scl for q=lq*4+j
#pragma unroll
      for (int dt = 0; dt < 4; ++dt)
#pragma unroll
        for (int j = 0; j < 4; ++j) o[dt][j] *= sj[j];
    }
#pragma unroll
    for (int tt = 0; tt < 4; ++tt)
#pragma unroll
      for (int j = 0; j < 4; ++j) s[tt][j] = __expf(s[tt][j] - mrow);
    float rs = ((s[0][0] + s[0][1]) + (s[0][2] + s[0][3])) +
               ((s[1][0] + s[1][1]) + (s[1][2] + s[1][3])) +
               ((s[2][0] + s[2][1]) + (s[2][2] + s[2][3])) +
               ((s[3][0] + s[3][1]) + (s[3][2] + s[3][3]));
    rs += __shfl_xor(rs, 16);
    rs += __shfl_xor(rs, 32);
    lrow += rs;

    // ---- P^T (key=16tt+4lq+j, q=lr) -> bf16 hi/lo in per-wave LDS, packed u32 ----
#pragma unroll
    for (int tt = 0; tt < 4; ++tt) {
      float e0 = s[tt][0], e1 = s[tt][1], e2 = s[tt][2], e3 = s[tt][3];
      *(uint32_t*)&Ph_s[w][lr][tt * 16 + lq * 4] = pkbf(e0, e1);
      *(uint32_t*)&Ph_s[w][lr][tt * 16 + lq * 4 + 2] = pkbf(e2, e3);
      float r0 = e0 - bf2f(f2bf(e0)), r1 = e1 - bf2f(f2bf(e1));
      float r2 = e2 - bf2f(f2bf(e2)), r3 = e3 - bf2f(f2bf(e3));
      *(uint32_t*)&Pl_s[w][lr][tt * 16 + lq * 4] = pkbf(r0, r1);
      *(uint32_t*)&Pl_s[w][lr][tt * 16 + lq * 4 + 2] = pkbf(r2, r3);
    }

    // ---- O += P·V via 3-term bf16 split (same wave: no barrier needed) ----
#pragma unroll
    for (int c = 0; c < 2; ++c) {
      const short8 ph = *(const short8*)&Ph_s[w][lr][c * 32 + lq * 8];
      const short8 pl = *(const short8*)&Pl_s[w][lr][c * 32 + lq * 8];
#pragma unroll
      for (int dt = 0; dt < 4; ++dt) {
        const short8 vh = *(const short8*)&Vh_s[dt * 16 + lr][c * 32 + lq * 8];
        const short8 vl = *(const short8*)&Vl_s[dt * 16 + lr][c * 32 + lq * 8];
        o[dt] = MFMA(ph, vh, o[dt]);
        o[dt] = MFMA(pl, vh, o[dt]);
        o[dt] = MFMA(ph, vl, o[dt]);
      }
    }

#pragma unroll
    for (int tt = 0; tt < 4; ++tt) mk[tt] = mk2[tt];
  }

  // ---- epilogue: O layout q=lq*4+j, d=dt*16+lr; l/m live on lane lr=q ----
  if constexpr (NSEG == 1) {
    const float linv = 1.0f / lrow;
#pragma unroll
    for (int j = 0; j < 4; ++j) {
      const float inv = __shfl(linv, lq * 4 + j);
      const size_t ob = ((size_t)b * TT + qrow + lq * 4 + j) * DD + lr;
#pragma unroll
      for (int dt = 0; dt < 4; ++dt) out[ob + dt * 16] = o[dt][j] * inv;
    }
  } else {
    const int grow = b * TT + qrow;  // wave's first global row
#pragma unroll
    for (int j = 0; j < 4; ++j) {
      const size_t r = (size_t)seg * (BB * TT) + grow + lq * 4 + j;
#pragma unroll
      for (int dt = 0; dt < 4; ++dt) Op[r * 64 + dt * 16 + lr] = o[dt][j];
    }
    if (lq == 0) {
      const size_t r = (size_t)seg * (BB * TT) + grow + lr;
      Mp[r] = mrow;
      Lp[r] = lrow;
    }
  }
}

// ---- merge NSEG partial results per row ----
__global__ __launch_bounds__(256) void combine_kernel(
    const float* __restrict__ Op, const float* __restrict__ Mp,
    const float* __restrict__ Lp, float* __restrict__ out, int nseg) {
  const int gid = blockIdx.x * 256 + threadIdx.x;
  const int r = gid >> 6, d = gid & 63;
  constexpr int ROWS = BB * TT;
  float m = -3.0e38f;
  for (int s = 0; s < nseg; ++s) m = fmaxf(m, Mp[s * ROWS + r]);
  float num = 0.f, den = 0.f;
  for (int s = 0; s < nseg; ++s) {
    const float e = __expf(Mp[s * ROWS + r] - m);
    den += Lp[s * ROWS + r] * e;
    num += Op[((size_t)s * ROWS + r) * 64 + d] * e;
  }
  out[(size_t)r * 64 + d] = num / den;
}

extern "C" void kernel_launch(void* const* d_in, const int* in_sizes, int n_in,
                              void* d_out, int out_size, void* d_ws, size_t ws_size,
                              hipStream_t stream) {
  const float* Q = (const float*)d_in[0];
  const float* K = (const float*)d_in[1];
  const float* V = (const float*)d_in[2];
  const float* mask = (const float*)d_in[3];
  float* out = (float*)d_out;

  const size_t NE = (size_t)BB * TT * DD;  // 1M elements per array
  const size_t ROWS = (size_t)BB * TT;     // 16384
  uint16_t* ws = (uint16_t*)d_ws;          // bf16 arrays: 12 MiB
  uint16_t* Qh = ws;
  uint16_t* Ql = ws + NE;
  uint16_t* Kh = ws + 2 * NE;
  uint16_t* Kl = ws + 3 * NE;
  uint16_t* Vh = ws + 4 * NE;
  uint16_t* Vl = ws + 5 * NE;

  const size_t bf_bytes = 6 * NE * 2;
  const size_t per_seg = ROWS * 64 * 4 + ROWS * 2 * 4;  // O + (m,l)
  int nseg = (ws_size >= bf_bytes + 4 * per_seg) ? 4
           : (ws_size >= bf_bytes + 2 * per_seg) ? 2 : 1;

  char* pbase = (char*)d_ws + bf_bytes;
  float* Op = (float*)pbase;
  float* Mp = (float*)(pbase + (size_t)nseg * ROWS * 64 * 4);
  float* Lp = Mp + (size_t)nseg * ROWS;

  prep_kernel<<<dim3(256), dim3(256), 0, stream>>>(Q, K, V, Qh, Ql, Kh, Kl, Vh, Vl);

  if (nseg == 4) {
    attn_kernel<4, 8><<<dim3(512), dim3(512), 0, stream>>>(
        mask, out, Op, Mp, Lp, Qh, Ql, Kh, Kl, Vh, Vl);
  } else if (nseg == 2) {
    attn_kernel<2, 8><<<dim3(256), dim3(512), 0, stream>>>(
        mask, out, Op, Mp, Lp, Qh, Ql, Kh, Kl, Vh, Vl);
  } else {
    attn_kernel<1, 4><<<dim3(256), dim3(256), 0, stream>>>(
        mask, out, Op, Mp, Lp, Qh, Ql, Kh, Kl, Vh, Vl);
  }
  if (nseg > 1) {
    combine_kernel<<<dim3((ROWS * 64) / 256), dim3(256), 0, stream>>>(Op, Mp, Lp, out, nseg);
  }
}